// Round 2
// baseline (507.566 us; speedup 1.0000x reference)
//
#include <hip/hip_runtime.h>
#include <math.h>

#define B_DIM 128
#define T_DIM 50
#define LEAF  4880
#define A_DIM 64
#define ATTN  128
#define RNN   128
#define NC    283
#define M_TOT (B_DIM*T_DIM)   // 6400
#define KSPLIT 5
#define NCH 153               // ceil(4880/32); chunk 152 has 16 valid k
#define WT_PLANE (NCH*512*8)  // 626688 ushort per plane (hi / lo)

using short8 = __attribute__((ext_vector_type(8))) short;
using short2v = __attribute__((ext_vector_type(2))) short;
using f32x4  = __attribute__((ext_vector_type(4))) float;

__device__ __forceinline__ float sigmoidf_(float x) {
  return 1.0f / (1.0f + __expf(-x));
}

// RNE fp32 -> bf16 bits
__device__ __forceinline__ unsigned short f32_to_bf16_rne(float f) {
  unsigned int u = __float_as_uint(f);
  unsigned int r = u + 0x7FFFu + ((u >> 16) & 1u);
  return (unsigned short)(r >> 16);
}
__device__ __forceinline__ float bf16_bits_to_f32(unsigned short b) {
  return __uint_as_float(((unsigned int)b) << 16);
}

// global -> LDS DMA, 16B per lane (dest must be wave-uniform base + lane*16)
__device__ __forceinline__ void gload_lds16(const void* g, void* l) {
  __builtin_amdgcn_global_load_lds(
      (const __attribute__((address_space(1))) unsigned int*)g,
      (__attribute__((address_space(3))) unsigned int*)l, 16, 0, 0);
}

// ---------------------------------------------------------------------------
// Pre-transpose W[4880,128] into MFMA B-fragment order, hi/lo bf16 planes.
// ---------------------------------------------------------------------------
__global__ __launch_bounds__(256) void k_prep_wt(
    const float* __restrict__ Wd, unsigned short* __restrict__ Wt) {
  const int u = blockIdx.x * 256 + threadIdx.x;   // 0 .. 78335 (NCH*512)
  const int c = u >> 9, rem = u & 511;
  const int nt = rem >> 6, lane = rem & 63;
  const int n = nt * 16 + (lane & 15);
  const int kb = c * 32 + ((lane >> 4) << 3);
  short8 h8, l8;
  #pragma unroll
  for (int j = 0; j < 8; ++j) {
    int k = kb + j;
    float v = (k < LEAF) ? Wd[(size_t)k * 128 + n] : 0.0f;
    unsigned short hb = f32_to_bf16_rne(v);
    unsigned short lb = f32_to_bf16_rne(v - bf16_bits_to_f32(hb));
    h8[j] = (short)hb;
    l8[j] = (short)lb;
  }
  *(short8*)&Wt[(size_t)u * 8] = h8;
  *(short8*)&Wt[(size_t)WT_PLANE + (size_t)u * 8] = l8;
}

// ---------------------------------------------------------------------------
// Big GEMM via MFMA, v4: occupancy + thin waves + DMA B-staging.
// R7 post-mortem: v3 (pipelined, 256t/4 waves) landed at 75us with ALL pipes
// <35% -- latency-bound on per-wave granularity: 4 waves/block, ~11 waves/CU,
// each wave 12 chained MFMA + 10 ds_read + 5 VMEM + ~30 VALU repack per
// barrier-to-barrier chunk (~5900 cyc wall per chunk).
// v4: 512 threads / 8 waves (wave = 16Mx32N, 6 MFMA), same 40KB LDS ->
// 4 blocks/CU = 32 waves/CU. B staged straight to LDS via global_load_lds
// width-16 (Wt already bf16 fragment-ordered; dest = uniform base + lane*16)
// -- no B regs, no B ds_writes. A reg-staged (needs fp32->bf16 hi/lo split),
// uniform 1 float2/thread, depth-2 prefetch, counted vmcnt(1) keeps next A
// in flight across the raw barrier (only lgkmcnt(0) drained).
// vmcnt FIFO per iter: enter [A(c+1)]; issue Blds(c+1)x2, A(c+2); compute;
// wait vmcnt(1) -> A(c+1)+Blds landed, A(c+2) stays in flight; storeA;
// lgkm(0); barrier. Empty memory-clobber asm pins the gl_lds-vs-A issue
// order (different addr spaces => compiler may otherwise reorder, breaking
// the count, which is load-bearing for B-in-LDS-before-barrier).
// Tail chunk: A addresses CLAMPED (min) not skipped -> uniform counts;
// clamped garbage is finite and killed by Wt's pre-zeroed k>=4880 rows.
// ---------------------------------------------------------------------------
__global__ __launch_bounds__(512, 8) void k_gemm_mfma(
    const float* __restrict__ Ax, const unsigned short* __restrict__ Wt,
    float* __restrict__ P) {
  __shared__ __align__(16) unsigned short As[2][2048];  // 8 KB  [buf][plane*1024 + frag]
  __shared__ __align__(16) unsigned short Bs[2][8192];  // 32 KB [buf][plane*4096 + slot*8]
  const int tid  = threadIdx.x;
  const int lane = tid & 63;
  const int w    = tid >> 6;
  const int msub = w & 1;        // M-subtile 0/1 (16 rows each)
  const int nq   = w >> 1;       // N-quarter 0..3 (32 cols each)
  const int M0   = blockIdx.x * 32;
  const int s    = blockIdx.y;
  const int c0   = (s * NCH) / KSPLIT;
  const int c1   = ((s + 1) * NCH) / KSPLIT;

  // A staging map (all 512 threads, uniform): row am = tid>>4, k-pair = tid&15.
  // 16 threads cover one row's 32 floats (128B contiguous, coalesced).
  const int am    = tid >> 4;
  const int kpair = tid & 15;
  const float* pA = Ax + (size_t)(M0 + am) * LEAF;
  // ushort index (within plane) matching the MFMA A-fragment read layout:
  // elem A[row][k] lives at (row>>4)*512 + ((row&15) + ((k>>3)<<4))*8 + (k&7)
  const int a_idx = (am >> 4) * 512 + ((am & 15) + ((kpair >> 2) << 4)) * 8 + (kpair & 3) * 2;

  f32x4 acc[2];
  #pragma unroll
  for (int i = 0; i < 2; ++i) {
    #pragma unroll
    for (int q = 0; q < 4; ++q) acc[i][q] = 0.0f;
  }

  float2 rA_a, rA_b;   // ping-pong A prefetch (depth 2)

  auto issueBlds = [&](int c, int p) {
    const size_t cb = ((size_t)c * 512 + tid) * 8;
    gload_lds16(&Wt[cb], &Bs[p][tid * 8]);
    gload_lds16(&Wt[(size_t)WT_PLANE + cb], &Bs[p][4096 + tid * 8]);
  };
  auto issueA = [&](int c, float2& ra) {
    int kk = c * 32 + kpair * 2;
    kk = min(kk, LEAF - 2);            // clamp (no skip): uniform vmcnt counts
    ra = *(const float2*)(pA + kk);
  };
  auto storeA = [&](int p, float2 ra) {
    unsigned short h0 = f32_to_bf16_rne(ra.x);
    unsigned short l0 = f32_to_bf16_rne(ra.x - bf16_bits_to_f32(h0));
    unsigned short h1 = f32_to_bf16_rne(ra.y);
    unsigned short l1 = f32_to_bf16_rne(ra.y - bf16_bits_to_f32(h1));
    short2v h2; h2[0] = (short)h0; h2[1] = (short)h1;
    short2v l2; l2[0] = (short)l0; l2[1] = (short)l1;
    *(short2v*)&As[p][a_idx] = h2;
    *(short2v*)&As[p][1024 + a_idx] = l2;
  };
  auto compute = [&](int p) {
    short8 a_hi = *(const short8*)&As[p][msub * 512 + lane * 8];
    short8 a_lo = *(const short8*)&As[p][1024 + msub * 512 + lane * 8];
    #pragma unroll
    for (int i = 0; i < 2; ++i) {
      const int nt = nq * 2 + i;
      short8 b_hi = *(const short8*)&Bs[p][(nt * 64 + lane) * 8];
      short8 b_lo = *(const short8*)&Bs[p][4096 + (nt * 64 + lane) * 8];
      acc[i] = __builtin_amdgcn_mfma_f32_16x16x32_bf16(a_hi, b_lo, acc[i], 0, 0, 0);
      acc[i] = __builtin_amdgcn_mfma_f32_16x16x32_bf16(a_lo, b_hi, acc[i], 0, 0, 0);
      acc[i] = __builtin_amdgcn_mfma_f32_16x16x32_bf16(a_hi, b_hi, acc[i], 0, 0, 0);
    }
  };

  // ---- prologue: stage chunk c0 into buf0; prime A depth-1 ----
  {
    float2 ta;
    issueBlds(c0, 0);
    asm volatile("" ::: "memory");     // pin issue order: Blds before A
    issueA(c0, ta);
    asm volatile("s_waitcnt vmcnt(0)" ::: "memory");
    storeA(0, ta);
    if (c0 + 1 < c1) issueA(c0 + 1, rA_a);   // queue entering iter c0: [A(c0+1)]
    asm volatile("s_waitcnt lgkmcnt(0)" ::: "memory");
    __builtin_amdgcn_s_barrier();
    asm volatile("" ::: "memory");
  }

#define GEMM_ITER(RAc, RAn)                                                   \
  {                                                                           \
    const int p = (c - c0) & 1;                                               \
    if (c + 1 < c1) {                                                         \
      issueBlds(c + 1, p ^ 1);          /* buf p^1 free after prev barrier */ \
      asm volatile("" ::: "memory");    /* pin: A(c+2) issues after Blds   */ \
      if (c + 2 < c1) issueA(c + 2, RAn);                                     \
      asm volatile("" ::: "memory");                                          \
    }                                                                         \
    compute(p);                                                               \
    if (c + 1 < c1) {                                                         \
      if (c + 2 < c1) { asm volatile("s_waitcnt vmcnt(1)" ::: "memory"); }    \
      else            { asm volatile("s_waitcnt vmcnt(0)" ::: "memory"); }    \
      storeA(p ^ 1, RAc);                                                     \
    }                                                                         \
    asm volatile("s_waitcnt lgkmcnt(0)" ::: "memory");                        \
    __builtin_amdgcn_s_barrier();                                             \
    asm volatile("" ::: "memory");                                            \
    ++c;                                                                      \
  }

  int c = c0;
  while (c < c1) {
    GEMM_ITER(rA_a, rA_b);
    if (c < c1) GEMM_ITER(rA_b, rA_a);
  }
#undef GEMM_ITER

  // epilogue: C/D layout col=lane&15, row=(lane>>4)*4+r
  float* outp = P + (size_t)s * ((size_t)M_TOT * 128);
  const int mrow = M0 + msub * 16 + ((lane >> 4) << 2);
  const int col0 = nq * 32 + (lane & 15);
  #pragma unroll
  for (int i = 0; i < 2; ++i) {
    #pragma unroll
    for (int r = 0; r < 4; ++r)
      outp[(size_t)(mrow + r) * 128 + col0 + i * 16] = acc[i][r];
  }
}

// ---------------------------------------------------------------------------
// Reduce KSPLIT partials + tanh (X aliases P slot 0; elementwise-safe).
// ---------------------------------------------------------------------------
__global__ __launch_bounds__(256) void k_reduce_tanh(
    float* __restrict__ P, float* __restrict__ X) {
  const size_t i = ((size_t)blockIdx.x * 256 + threadIdx.x) * 4;
  float4 a = *(const float4*)&P[i];
  #pragma unroll
  for (int s = 1; s < KSPLIT; ++s) {
    float4 b = *(const float4*)&P[(size_t)s * (M_TOT * 128) + i];
    a.x += b.x; a.y += b.y; a.z += b.z; a.w += b.w;
  }
  a.x = tanhf(a.x); a.y = tanhf(a.y); a.z = tanhf(a.z); a.w = tanhf(a.w);
  *(float4*)&X[i] = a;
}

// ---------------------------------------------------------------------------
// Generic small GEMM: C[M,N] = A[M,K] @ Bw[N,K]^T + bias  (opt sigmoid*mask)
// ---------------------------------------------------------------------------
template<int K, int ACT>
__global__ __launch_bounds__(256) void k_gemm_bn(
    const float* __restrict__ A, const float* __restrict__ Bw,
    const float* __restrict__ bias, const float* __restrict__ maskv,
    float* __restrict__ C, int N, int ldc) {
  __shared__ __align__(16) float Asm[32][K + 4];
  const int tid = threadIdx.x;
  const int m0 = blockIdx.x * 32;
  const int n0 = blockIdx.y * 64;
  constexpr int K4 = K / 4;

  #pragma unroll
  for (int i = 0; i < (32 * K4) / 256; ++i) {
    int idx = tid + i * 256;
    int row = idx / K4, k4 = idx % K4;
    float4 v = *(const float4*)&A[(size_t)(m0 + row) * K + k4 * 4];
    *(float4*)&Asm[row][k4 * 4] = v;
  }
  __syncthreads();

  const int n2 = tid & 31, mg = tid >> 5;
  const int n = n0 + n2 * 2;
  const int ns0 = min(n, N - 1), ns1 = min(n + 1, N - 1);
  const float* Bp0 = Bw + (size_t)ns0 * K;
  const float* Bp1 = Bw + (size_t)ns1 * K;

  float acc[4][2] = {};
  #pragma unroll 4
  for (int k = 0; k < K; k += 4) {
    float4 b0 = *(const float4*)&Bp0[k];
    float4 b1 = *(const float4*)&Bp1[k];
    #pragma unroll
    for (int r = 0; r < 4; ++r) {
      float4 a = *(const float4*)&Asm[mg * 4 + r][k];
      acc[r][0] += a.x * b0.x + a.y * b0.y + a.z * b0.z + a.w * b0.w;
      acc[r][1] += a.x * b1.x + a.y * b1.y + a.z * b1.z + a.w * b1.w;
    }
  }

  #pragma unroll
  for (int r = 0; r < 4; ++r) {
    int m = m0 + mg * 4 + r;
    #pragma unroll
    for (int c = 0; c < 2; ++c) {
      int nn = n + c;
      if (nn < N) {
        float v = acc[r][c] + bias[nn];
        if (ACT) v = sigmoidf_(v) * maskv[m];
        C[(size_t)m * ldc + nn] = v;
      }
    }
  }
}

// ---------------------------------------------------------------------------
// GRU scan v3 (R5-proven). One block per batch row; 512 threads.
// Weights pre-rotated at load (register arrays use unroll-constant indices
// only). n-gate bias INSIDE r*: n = tanh(xn + r*(Wn.h + bn)).
// ---------------------------------------------------------------------------
__global__ __launch_bounds__(512) void k_gru(
    const float* __restrict__ xW, const float* __restrict__ Whh,
    const float* __restrict__ bhh, float* __restrict__ Hout) {
  const int b = blockIdx.x;
  const int tid = threadIdx.x;
  const int j  = tid >> 2;
  const int qf = tid & 3;
  __shared__ __align__(16) float hs[2][128];

  float4 wr[8], wz[8], wn[8];
  {
    const float* pr = Whh + (size_t)j * 128 + qf * 32;
    const float* pz = Whh + (size_t)(j + 128) * 128 + qf * 32;
    const float* pn = Whh + (size_t)(j + 256) * 128 + qf * 32;
    #pragma unroll
    for (int k = 0; k < 8; ++k) {
      const int c = (k + qf * 2) & 7;   // rotation folded into the LOAD
      wr[k] = *(const float4*)(pr + c * 4);
      wz[k] = *(const float4*)(pz + c * 4);
      wn[k] = *(const float4*)(pn + c * 4);
    }
  }
  const float br = bhh[j], bz = bhh[j + 128], bn_ = bhh[j + 256];

  if (tid < 128) hs[0][tid] = 0.0f;
  const float* xwb = xW + (size_t)b * 50 * 384;
  float xr = 0.f, xz = 0.f, xn = 0.f;
  if (qf == 0) { xr = xwb[j]; xz = xwb[128 + j]; xn = xwb[256 + j]; }
  __syncthreads();

  int cur = 0;
  for (int t = 0; t < 50; ++t) {
    float nxr = 0.f, nxz = 0.f, nxn = 0.f;
    if (qf == 0 && t + 1 < 50) {
      const float* xwn = xwb + (size_t)(t + 1) * 384;
      nxr = xwn[j]; nxz = xwn[128 + j]; nxn = xwn[256 + j];
    }

    float ar = 0.f, az = 0.f, an = 0.f;
    #pragma unroll
    for (int k = 0; k < 8; ++k) {
      const int c = (k + qf * 2) & 7;   // runtime -> LDS address only
      float4 hv = *(const float4*)&hs[cur][qf * 32 + c * 4];
      ar += wr[k].x * hv.x + wr[k].y * hv.y + wr[k].z * hv.z + wr[k].w * hv.w;
      az += wz[k].x * hv.x + wz[k].y * hv.y + wz[k].z * hv.z + wz[k].w * hv.w;
      an += wn[k].x * hv.x + wn[k].y * hv.y + wn[k].z * hv.z + wn[k].w * hv.w;
    }
    ar += __shfl_xor(ar, 1); ar += __shfl_xor(ar, 2);
    az += __shfl_xor(az, 1); az += __shfl_xor(az, 2);
    an += __shfl_xor(an, 1); an += __shfl_xor(an, 2);

    if (qf == 0) {
      float r = sigmoidf_(xr + ar + br);
      float z = sigmoidf_(xz + az + bz);
      float nn = tanhf(xn + r * (an + bn_));   // bias INSIDE r*
      float h = (1.f - z) * nn + z * hs[cur][j];
      hs[cur ^ 1][j] = h;
      Hout[(size_t)(b * 50 + t) * 128 + j] = h;
    }
    __syncthreads();
    cur ^= 1;
    xr = nxr; xz = nxz; xn = nxn;
  }
}

// ---------------------------------------------------------------------------
// Attention: per (b,t) block (6400 blocks, 128 threads).
// ---------------------------------------------------------------------------
__global__ __launch_bounds__(128) void k_attn(
    const float* __restrict__ H2, const int* __restrict__ F,
    const float* __restrict__ emb, float* __restrict__ S) {
  const int m = blockIdx.x;
  const int tid = threadIdx.x;
  __shared__ __align__(16) float outs[128];
  __shared__ __align__(16) float Ls[64][132];
  __shared__ float hls[64];
  __shared__ float wts[64];
  __shared__ int fs[64];

  outs[tid] = H2[(size_t)m * 128 + tid];
  if (tid < 64) fs[tid] = F[(size_t)m * 64 + tid];
  __syncthreads();

  #pragma unroll
  for (int i = 0; i < 16; ++i) {
    int idx = tid + i * 128;
    int a = idx >> 5, c4 = idx & 31;
    float4 v = *(const float4*)&emb[(size_t)fs[a] * 128 + c4 * 4];
    *(float4*)&Ls[a][c4 * 4] = v;
  }
  __syncthreads();

  {
    const int a = tid >> 1, hf = tid & 1;
    float sum = 0.f;
    #pragma unroll
    for (int j = 0; j < 16; ++j) {
      float4 lv = *(const float4*)&Ls[a][hf * 64 + j * 4];
      float4 ov = *(const float4*)&outs[hf * 64 + j * 4];
      sum += lv.x * ov.x + lv.y * ov.y + lv.z * ov.z + lv.w * ov.w;
    }
    float other = __shfl_xor(sum, 1);
    sum += other;
    if (hf == 0) hls[a] = sum + (fs[a] > 0 ? 0.0f : -1e30f);
  }
  __syncthreads();

  if (tid < 64) {
    float v = hls[tid];
    float mx = v;
    #pragma unroll
    for (int o = 32; o; o >>= 1) mx = fmaxf(mx, __shfl_xor(mx, o));
    float e = __expf(v - mx);
    float sm = e;
    #pragma unroll
    for (int o = 32; o; o >>= 1) sm += __shfl_xor(sm, o);
    wts[tid] = e / sm;
  }
  __syncthreads();

  float kv = 0.f;
  #pragma unroll 8
  for (int a2 = 0; a2 < 64; ++a2) kv += wts[a2] * Ls[a2][tid];

  S[(size_t)m * 256 + tid] = outs[tid];
  S[(size_t)m * 256 + 128 + tid] = kv;
}

// ---------------------------------------------------------------------------
extern "C" void kernel_launch(void* const* d_in, const int* in_sizes, int n_in,
                              void* d_out, int out_size, void* d_ws, size_t ws_size,
                              hipStream_t stream) {
  const float* inputs_x  = (const float*)d_in[0];
  const int*   inputs_f  = (const int*)d_in[1];
  const float* mask_seqs = (const float*)d_in[2];
  const float* dag_emb   = (const float*)d_in[3];
  const float* embed_a   = (const float*)d_in[4];
  const float* Wih0 = (const float*)d_in[5];
  const float* Whh0 = (const float*)d_in[6];
  const float* bih0 = (const float*)d_in[7];
  const float* bhh0 = (const float*)d_in[8];
  const float* Wih1 = (const float*)d_in[9];
  const float* Whh1 = (const float*)d_in[10];
  const float* bih1 = (const float*)d_in[11];
  const float* bhh1 = (const float*)d_in[12];
  const float* fc_w = (const float*)d_in[13];
  const float* fc_b = (const float*)d_in[14];
  float* out = (float*)d_out;

  float* ws = (float*)d_ws;
  // Footprint identical to R5/R6 (proven): 5*819200 + 2457600 + 2*819200 floats.
  float* P  = ws;
  float* X  = P;                       // aliases P slot 0 (reduce in-place safe)
  float* S  = P + 819200;              // aliases P slots 1-2 (P dead after reduce)
  float* xW = ws + KSPLIT * 819200;
  float* H1 = xW + 2457600;
  float* H2 = H1 + 819200;
  // Wt (2.5 MB bf16) aliases H1+H2 (6.5 MB): dead before k_gru writes H1.
  unsigned short* Wt = (unsigned short*)H1;

  k_prep_wt<<<306, 256, 0, stream>>>(dag_emb, Wt);
  k_gemm_mfma<<<dim3(200, KSPLIT), 512, 0, stream>>>(inputs_x, Wt, P);
  k_reduce_tanh<<<800, 256, 0, stream>>>(P, X);
  k_gemm_bn<128, 0><<<dim3(200, 6), 256, 0, stream>>>(X, Wih0, bih0, nullptr, xW, 384, 384);
  k_gru<<<128, 512, 0, stream>>>(xW, Whh0, bhh0, H1);
  k_gemm_bn<128, 0><<<dim3(200, 6), 256, 0, stream>>>(H1, Wih1, bih1, nullptr, xW, 384, 384);
  k_gru<<<128, 512, 0, stream>>>(xW, Whh1, bhh1, H2);
  k_attn<<<6400, 128, 0, stream>>>(H2, inputs_f, embed_a, S);
  k_gemm_bn<256, 1><<<dim3(200, 5), 256, 0, stream>>>(S, fc_w, fc_b, mask_seqs, out, 283, 283);
}

// Round 3
// 506.376 us; speedup vs baseline: 1.0023x; 1.0023x over previous
//
#include <hip/hip_runtime.h>
#include <math.h>

#define B_DIM 128
#define T_DIM 50
#define LEAF  4880
#define A_DIM 64
#define ATTN  128
#define RNN   128
#define NC    283
#define M_TOT (B_DIM*T_DIM)   // 6400
#define KSPLIT 5
#define NCH 153               // ceil(4880/32); chunk 152 has 16 valid k
#define WT_PLANE (NCH*512*8)  // 626688 ushort per plane (hi / lo)

using short8 = __attribute__((ext_vector_type(8))) short;
using short2v = __attribute__((ext_vector_type(2))) short;
using f32x4  = __attribute__((ext_vector_type(4))) float;

__device__ __forceinline__ float sigmoidf_(float x) {
  return 1.0f / (1.0f + __expf(-x));
}

// RNE fp32 -> bf16 bits
__device__ __forceinline__ unsigned short f32_to_bf16_rne(float f) {
  unsigned int u = __float_as_uint(f);
  unsigned int r = u + 0x7FFFu + ((u >> 16) & 1u);
  return (unsigned short)(r >> 16);
}
__device__ __forceinline__ float bf16_bits_to_f32(unsigned short b) {
  return __uint_as_float(((unsigned int)b) << 16);
}

// ---------------------------------------------------------------------------
// Pre-transpose W[4880,128] into MFMA B-fragment order, hi/lo bf16 planes.
// ---------------------------------------------------------------------------
__global__ __launch_bounds__(256) void k_prep_wt(
    const float* __restrict__ Wd, unsigned short* __restrict__ Wt) {
  const int u = blockIdx.x * 256 + threadIdx.x;   // 0 .. 78335 (NCH*512)
  const int c = u >> 9, rem = u & 511;
  const int nt = rem >> 6, lane = rem & 63;
  const int n = nt * 16 + (lane & 15);
  const int kb = c * 32 + ((lane >> 4) << 3);
  short8 h8, l8;
  #pragma unroll
  for (int j = 0; j < 8; ++j) {
    int k = kb + j;
    float v = (k < LEAF) ? Wd[(size_t)k * 128 + n] : 0.0f;
    unsigned short hb = f32_to_bf16_rne(v);
    unsigned short lb = f32_to_bf16_rne(v - bf16_bits_to_f32(hb));
    h8[j] = (short)hb;
    l8[j] = (short)lb;
  }
  *(short8*)&Wt[(size_t)u * 8] = h8;
  *(short8*)&Wt[(size_t)WT_PLANE + (size_t)u * 8] = l8;
}

// ---------------------------------------------------------------------------
// Big GEMM via MFMA, v5: B bypasses LDS entirely.
// R8 post-mortem: v4 (512t, 66% occ) still 80us with every pipe <20% --
// per-block-chunk CU budget (6200cyc wall / 4 blocks = 1550cyc) matches the
// SUM of port usage: LDS 72KB (~800cyc) + MFMA 233 + VMEM ~300 + VALU ~280.
// The kernel is bound by aggregate port pressure, chiefly LDS bytes.
// (Bank-conflict constant 2937600 = 96cyc x 153chunks x 200 decoded as the
// A-staging writes -- structural 4-bank row aliasing; reads are phase-
// contiguous/free.)
// v5: waves remapped to 32Mx16N (each wave owns nt=w, computes both msub):
// B fragments become wave-private -> read global->VGPR straight from the
// fragment-ordered Wt (1KB/wave/chunk, coalesced, L2-resident, read once
// per block). No B LDS writes or reads: LDS/blk/chunk 72KB->40KB, and the
// barrier now only protects the 8KB A double-buffer. B prefetch depth-1 in
// ping-ponged regs rides the vmcnt stream across barriers; counted waits
// drain exactly {B(c)x2, A(c+1)} each iter (vmcnt 3/2/0 at tail). A path
// (staging map, hi/lo convert, clamp tail) identical to v4.
// Arithmetic identical (3-MFMA hi/lo) -> absmax bit-identical.
// ---------------------------------------------------------------------------
__global__ __launch_bounds__(512, 8) void k_gemm_mfma(
    const float* __restrict__ Ax, const unsigned short* __restrict__ Wt,
    float* __restrict__ P) {
  __shared__ __align__(16) unsigned short As[2][2048];  // 8 KB [buf][plane*1024 + frag]
  const int tid  = threadIdx.x;
  const int lane = tid & 63;
  const int w    = tid >> 6;     // wave id = nt tile (16 cols each)
  const int M0   = blockIdx.x * 32;
  const int s    = blockIdx.y;
  const int c0   = (s * NCH) / KSPLIT;
  const int c1   = ((s + 1) * NCH) / KSPLIT;

  // A staging map (all 512 threads, uniform): row am = tid>>4, k-pair = tid&15.
  // 16 threads cover one row's 32 floats (128B contiguous, coalesced).
  const int am    = tid >> 4;
  const int kpair = tid & 15;
  const float* pA = Ax + (size_t)(M0 + am) * LEAF;
  // ushort index (within plane) matching the MFMA A-fragment read layout:
  // elem A[row][k] lives at (row>>4)*512 + ((row&15) + ((k>>3)<<4))*8 + (k&7)
  const int a_idx = (am >> 4) * 512 + ((am & 15) + ((kpair >> 2) << 4)) * 8 + (kpair & 3) * 2;

  f32x4 acc[2];
  #pragma unroll
  for (int i = 0; i < 2; ++i) {
    #pragma unroll
    for (int q = 0; q < 4; ++q) acc[i][q] = 0.0f;
  }

  float2 rA_a, rA_b;                 // ping-pong A prefetch (depth 2)
  short8 bh_a, bl_a, bh_b, bl_b;     // ping-pong B fragments (depth 1)

  auto issueB = [&](int c, short8& bh, short8& bl) {
    const size_t o = ((size_t)c * 512 + w * 64 + lane) * 8;
    bh = *(const short8*)&Wt[o];
    bl = *(const short8*)&Wt[(size_t)WT_PLANE + o];
  };
  auto issueA = [&](int c, float2& ra) {
    int kk = c * 32 + kpair * 2;
    kk = min(kk, LEAF - 2);            // clamp (no skip): uniform vmcnt counts
    ra = *(const float2*)(pA + kk);
  };
  auto storeA = [&](int p, float2 ra) {
    unsigned short h0 = f32_to_bf16_rne(ra.x);
    unsigned short l0 = f32_to_bf16_rne(ra.x - bf16_bits_to_f32(h0));
    unsigned short h1 = f32_to_bf16_rne(ra.y);
    unsigned short l1 = f32_to_bf16_rne(ra.y - bf16_bits_to_f32(h1));
    short2v h2; h2[0] = (short)h0; h2[1] = (short)h1;
    short2v l2; l2[0] = (short)l0; l2[1] = (short)l1;
    *(short2v*)&As[p][a_idx] = h2;
    *(short2v*)&As[p][1024 + a_idx] = l2;
  };
  auto compute = [&](int p, const short8& bh, const short8& bl) {
    short8 a_hi0 = *(const short8*)&As[p][lane * 8];
    short8 a_hi1 = *(const short8*)&As[p][512 + lane * 8];
    short8 a_lo0 = *(const short8*)&As[p][1024 + lane * 8];
    short8 a_lo1 = *(const short8*)&As[p][1536 + lane * 8];
    acc[0] = __builtin_amdgcn_mfma_f32_16x16x32_bf16(a_hi0, bl, acc[0], 0, 0, 0);
    acc[0] = __builtin_amdgcn_mfma_f32_16x16x32_bf16(a_lo0, bh, acc[0], 0, 0, 0);
    acc[0] = __builtin_amdgcn_mfma_f32_16x16x32_bf16(a_hi0, bh, acc[0], 0, 0, 0);
    acc[1] = __builtin_amdgcn_mfma_f32_16x16x32_bf16(a_hi1, bl, acc[1], 0, 0, 0);
    acc[1] = __builtin_amdgcn_mfma_f32_16x16x32_bf16(a_lo1, bh, acc[1], 0, 0, 0);
    acc[1] = __builtin_amdgcn_mfma_f32_16x16x32_bf16(a_hi1, bh, acc[1], 0, 0, 0);
  };

  // ---- prologue ----
  {
    float2 ta;
    issueA(c0, ta);
    asm volatile("s_waitcnt vmcnt(0)" ::: "memory");
    storeA(0, ta);
    issueB(c0, bh_a, bl_a);                      // 2 loads
    asm volatile("" ::: "memory");
    if (c0 + 1 < c1) issueA(c0 + 1, rA_a);       // 1 load
    asm volatile("s_waitcnt lgkmcnt(0)" ::: "memory");
    __builtin_amdgcn_s_barrier();
    asm volatile("" ::: "memory");
    // outstanding entering loop: [B(c0) x2, A(c0+1)]
  }

  // Per iter: outstanding on entry = [B(c) x2, A(c+1)] (from prev iter).
  // Issue B(c+1)x2, A(c+2); counted wait drains exactly the entry set;
  // compute with B(c); storeA(A(c+1)); lgkm; barrier.
#define GEMM_ITER(BHc, BLc, BHn, BLn, RAc, RAn)                               \
  {                                                                           \
    const int p = (c - c0) & 1;                                               \
    const bool has1 = (c + 1 < c1), has2 = (c + 2 < c1);                      \
    if (has1) { issueB(c + 1, BHn, BLn); asm volatile("" ::: "memory"); }     \
    if (has2) { issueA(c + 2, RAn);      asm volatile("" ::: "memory"); }     \
    if (has1) {                                                               \
      if (has2) { asm volatile("s_waitcnt vmcnt(3)" ::: "memory"); }          \
      else      { asm volatile("s_waitcnt vmcnt(2)" ::: "memory"); }          \
    } else      { asm volatile("s_waitcnt vmcnt(0)" ::: "memory"); }          \
    compute(p, BHc, BLc);                                                     \
    if (has1) storeA(p ^ 1, RAc);                                             \
    asm volatile("s_waitcnt lgkmcnt(0)" ::: "memory");                        \
    __builtin_amdgcn_s_barrier();                                             \
    asm volatile("" ::: "memory");                                            \
    ++c;                                                                      \
  }

  int c = c0;
  while (c < c1) {
    GEMM_ITER(bh_a, bl_a, bh_b, bl_b, rA_a, rA_b);
    if (c < c1) GEMM_ITER(bh_b, bl_b, bh_a, bl_a, rA_b, rA_a);
  }
#undef GEMM_ITER

  // epilogue: C/D layout col=lane&15, row=(lane>>4)*4+r ; cols = w*16..w*16+15
  float* outp = P + (size_t)s * ((size_t)M_TOT * 128);
  const int rbase = M0 + ((lane >> 4) << 2);
  const int col0  = w * 16 + (lane & 15);
  #pragma unroll
  for (int i = 0; i < 2; ++i) {
    #pragma unroll
    for (int r = 0; r < 4; ++r)
      outp[(size_t)(rbase + i * 16 + r) * 128 + col0] = acc[i][r];
  }
}

// ---------------------------------------------------------------------------
// Reduce KSPLIT partials + tanh (X aliases P slot 0; elementwise-safe).
// ---------------------------------------------------------------------------
__global__ __launch_bounds__(256) void k_reduce_tanh(
    float* __restrict__ P, float* __restrict__ X) {
  const size_t i = ((size_t)blockIdx.x * 256 + threadIdx.x) * 4;
  float4 a = *(const float4*)&P[i];
  #pragma unroll
  for (int s = 1; s < KSPLIT; ++s) {
    float4 b = *(const float4*)&P[(size_t)s * (M_TOT * 128) + i];
    a.x += b.x; a.y += b.y; a.z += b.z; a.w += b.w;
  }
  a.x = tanhf(a.x); a.y = tanhf(a.y); a.z = tanhf(a.z); a.w = tanhf(a.w);
  *(float4*)&X[i] = a;
}

// ---------------------------------------------------------------------------
// Generic small GEMM: C[M,N] = A[M,K] @ Bw[N,K]^T + bias  (opt sigmoid*mask)
// ---------------------------------------------------------------------------
template<int K, int ACT>
__global__ __launch_bounds__(256) void k_gemm_bn(
    const float* __restrict__ A, const float* __restrict__ Bw,
    const float* __restrict__ bias, const float* __restrict__ maskv,
    float* __restrict__ C, int N, int ldc) {
  __shared__ __align__(16) float Asm[32][K + 4];
  const int tid = threadIdx.x;
  const int m0 = blockIdx.x * 32;
  const int n0 = blockIdx.y * 64;
  constexpr int K4 = K / 4;

  #pragma unroll
  for (int i = 0; i < (32 * K4) / 256; ++i) {
    int idx = tid + i * 256;
    int row = idx / K4, k4 = idx % K4;
    float4 v = *(const float4*)&A[(size_t)(m0 + row) * K + k4 * 4];
    *(float4*)&Asm[row][k4 * 4] = v;
  }
  __syncthreads();

  const int n2 = tid & 31, mg = tid >> 5;
  const int n = n0 + n2 * 2;
  const int ns0 = min(n, N - 1), ns1 = min(n + 1, N - 1);
  const float* Bp0 = Bw + (size_t)ns0 * K;
  const float* Bp1 = Bw + (size_t)ns1 * K;

  float acc[4][2] = {};
  #pragma unroll 4
  for (int k = 0; k < K; k += 4) {
    float4 b0 = *(const float4*)&Bp0[k];
    float4 b1 = *(const float4*)&Bp1[k];
    #pragma unroll
    for (int r = 0; r < 4; ++r) {
      float4 a = *(const float4*)&Asm[mg * 4 + r][k];
      acc[r][0] += a.x * b0.x + a.y * b0.y + a.z * b0.z + a.w * b0.w;
      acc[r][1] += a.x * b1.x + a.y * b1.y + a.z * b1.z + a.w * b1.w;
    }
  }

  #pragma unroll
  for (int r = 0; r < 4; ++r) {
    int m = m0 + mg * 4 + r;
    #pragma unroll
    for (int c = 0; c < 2; ++c) {
      int nn = n + c;
      if (nn < N) {
        float v = acc[r][c] + bias[nn];
        if (ACT) v = sigmoidf_(v) * maskv[m];
        C[(size_t)m * ldc + nn] = v;
      }
    }
  }
}

// ---------------------------------------------------------------------------
// GRU scan v3 (R5-proven). One block per batch row; 512 threads.
// Weights pre-rotated at load (register arrays use unroll-constant indices
// only). n-gate bias INSIDE r*: n = tanh(xn + r*(Wn.h + bn)).
// ---------------------------------------------------------------------------
__global__ __launch_bounds__(512) void k_gru(
    const float* __restrict__ xW, const float* __restrict__ Whh,
    const float* __restrict__ bhh, float* __restrict__ Hout) {
  const int b = blockIdx.x;
  const int tid = threadIdx.x;
  const int j  = tid >> 2;
  const int qf = tid & 3;
  __shared__ __align__(16) float hs[2][128];

  float4 wr[8], wz[8], wn[8];
  {
    const float* pr = Whh + (size_t)j * 128 + qf * 32;
    const float* pz = Whh + (size_t)(j + 128) * 128 + qf * 32;
    const float* pn = Whh + (size_t)(j + 256) * 128 + qf * 32;
    #pragma unroll
    for (int k = 0; k < 8; ++k) {
      const int c = (k + qf * 2) & 7;   // rotation folded into the LOAD
      wr[k] = *(const float4*)(pr + c * 4);
      wz[k] = *(const float4*)(pz + c * 4);
      wn[k] = *(const float4*)(pn + c * 4);
    }
  }
  const float br = bhh[j], bz = bhh[j + 128], bn_ = bhh[j + 256];

  if (tid < 128) hs[0][tid] = 0.0f;
  const float* xwb = xW + (size_t)b * 50 * 384;
  float xr = 0.f, xz = 0.f, xn = 0.f;
  if (qf == 0) { xr = xwb[j]; xz = xwb[128 + j]; xn = xwb[256 + j]; }
  __syncthreads();

  int cur = 0;
  for (int t = 0; t < 50; ++t) {
    float nxr = 0.f, nxz = 0.f, nxn = 0.f;
    if (qf == 0 && t + 1 < 50) {
      const float* xwn = xwb + (size_t)(t + 1) * 384;
      nxr = xwn[j]; nxz = xwn[128 + j]; nxn = xwn[256 + j];
    }

    float ar = 0.f, az = 0.f, an = 0.f;
    #pragma unroll
    for (int k = 0; k < 8; ++k) {
      const int c = (k + qf * 2) & 7;   // runtime -> LDS address only
      float4 hv = *(const float4*)&hs[cur][qf * 32 + c * 4];
      ar += wr[k].x * hv.x + wr[k].y * hv.y + wr[k].z * hv.z + wr[k].w * hv.w;
      az += wz[k].x * hv.x + wz[k].y * hv.y + wz[k].z * hv.z + wz[k].w * hv.w;
      an += wn[k].x * hv.x + wn[k].y * hv.y + wn[k].z * hv.z + wn[k].w * hv.w;
    }
    ar += __shfl_xor(ar, 1); ar += __shfl_xor(ar, 2);
    az += __shfl_xor(az, 1); az += __shfl_xor(az, 2);
    an += __shfl_xor(an, 1); an += __shfl_xor(an, 2);

    if (qf == 0) {
      float r = sigmoidf_(xr + ar + br);
      float z = sigmoidf_(xz + az + bz);
      float nn = tanhf(xn + r * (an + bn_));   // bias INSIDE r*
      float h = (1.f - z) * nn + z * hs[cur][j];
      hs[cur ^ 1][j] = h;
      Hout[(size_t)(b * 50 + t) * 128 + j] = h;
    }
    __syncthreads();
    cur ^= 1;
    xr = nxr; xz = nxz; xn = nxn;
  }
}

// ---------------------------------------------------------------------------
// Attention: per (b,t) block (6400 blocks, 128 threads).
// ---------------------------------------------------------------------------
__global__ __launch_bounds__(128) void k_attn(
    const float* __restrict__ H2, const int* __restrict__ F,
    const float* __restrict__ emb, float* __restrict__ S) {
  const int m = blockIdx.x;
  const int tid = threadIdx.x;
  __shared__ __align__(16) float outs[128];
  __shared__ __align__(16) float Ls[64][132];
  __shared__ float hls[64];
  __shared__ float wts[64];
  __shared__ int fs[64];

  outs[tid] = H2[(size_t)m * 128 + tid];
  if (tid < 64) fs[tid] = F[(size_t)m * 64 + tid];
  __syncthreads();

  #pragma unroll
  for (int i = 0; i < 16; ++i) {
    int idx = tid + i * 128;
    int a = idx >> 5, c4 = idx & 31;
    float4 v = *(const float4*)&emb[(size_t)fs[a] * 128 + c4 * 4];
    *(float4*)&Ls[a][c4 * 4] = v;
  }
  __syncthreads();

  {
    const int a = tid >> 1, hf = tid & 1;
    float sum = 0.f;
    #pragma unroll
    for (int j = 0; j < 16; ++j) {
      float4 lv = *(const float4*)&Ls[a][hf * 64 + j * 4];
      float4 ov = *(const float4*)&outs[hf * 64 + j * 4];
      sum += lv.x * ov.x + lv.y * ov.y + lv.z * ov.z + lv.w * ov.w;
    }
    float other = __shfl_xor(sum, 1);
    sum += other;
    if (hf == 0) hls[a] = sum + (fs[a] > 0 ? 0.0f : -1e30f);
  }
  __syncthreads();

  if (tid < 64) {
    float v = hls[tid];
    float mx = v;
    #pragma unroll
    for (int o = 32; o; o >>= 1) mx = fmaxf(mx, __shfl_xor(mx, o));
    float e = __expf(v - mx);
    float sm = e;
    #pragma unroll
    for (int o = 32; o; o >>= 1) sm += __shfl_xor(sm, o);
    wts[tid] = e / sm;
  }
  __syncthreads();

  float kv = 0.f;
  #pragma unroll 8
  for (int a2 = 0; a2 < 64; ++a2) kv += wts[a2] * Ls[a2][tid];

  S[(size_t)m * 256 + tid] = outs[tid];
  S[(size_t)m * 256 + 128 + tid] = kv;
}

// ---------------------------------------------------------------------------
extern "C" void kernel_launch(void* const* d_in, const int* in_sizes, int n_in,
                              void* d_out, int out_size, void* d_ws, size_t ws_size,
                              hipStream_t stream) {
  const float* inputs_x  = (const float*)d_in[0];
  const int*   inputs_f  = (const int*)d_in[1];
  const float* mask_seqs = (const float*)d_in[2];
  const float* dag_emb   = (const float*)d_in[3];
  const float* embed_a   = (const float*)d_in[4];
  const float* Wih0 = (const float*)d_in[5];
  const float* Whh0 = (const float*)d_in[6];
  const float* bih0 = (const float*)d_in[7];
  const float* bhh0 = (const float*)d_in[8];
  const float* Wih1 = (const float*)d_in[9];
  const float* Whh1 = (const float*)d_in[10];
  const float* bih1 = (const float*)d_in[11];
  const float* bhh1 = (const float*)d_in[12];
  const float* fc_w = (const float*)d_in[13];
  const float* fc_b = (const float*)d_in[14];
  float* out = (float*)d_out;

  float* ws = (float*)d_ws;
  // Footprint identical to R5/R6 (proven): 5*819200 + 2457600 + 2*819200 floats.
  float* P  = ws;
  float* X  = P;                       // aliases P slot 0 (reduce in-place safe)
  float* S  = P + 819200;              // aliases P slots 1-2 (P dead after reduce)
  float* xW = ws + KSPLIT * 819200;
  float* H1 = xW + 2457600;
  float* H2 = H1 + 819200;
  // Wt (2.5 MB bf16) aliases H1+H2 (6.5 MB): dead before k_gru writes H1.
  unsigned short* Wt = (unsigned short*)H1;

  k_prep_wt<<<306, 256, 0, stream>>>(dag_emb, Wt);
  k_gemm_mfma<<<dim3(200, KSPLIT), 512, 0, stream>>>(inputs_x, Wt, P);
  k_reduce_tanh<<<800, 256, 0, stream>>>(P, X);
  k_gemm_bn<128, 0><<<dim3(200, 6), 256, 0, stream>>>(X, Wih0, bih0, nullptr, xW, 384, 384);
  k_gru<<<128, 512, 0, stream>>>(xW, Whh0, bhh0, H1);
  k_gemm_bn<128, 0><<<dim3(200, 6), 256, 0, stream>>>(H1, Wih1, bih1, nullptr, xW, 384, 384);
  k_gru<<<128, 512, 0, stream>>>(xW, Whh1, bhh1, H2);
  k_attn<<<6400, 128, 0, stream>>>(H2, inputs_f, embed_a, S);
  k_gemm_bn<256, 1><<<dim3(200, 5), 256, 0, stream>>>(S, fc_w, fc_b, mask_seqs, out, 283, 283);
}

// Round 4
// 488.387 us; speedup vs baseline: 1.0393x; 1.0368x over previous
//
#include <hip/hip_runtime.h>
#include <math.h>

#define B_DIM 128
#define T_DIM 50
#define LEAF  4880
#define A_DIM 64
#define ATTN  128
#define RNN   128
#define NC    283
#define M_TOT (B_DIM*T_DIM)   // 6400
#define KSPLIT 5
#define NCH 153               // ceil(4880/32); chunk 152 has 16 valid k
#define WT_PLANE (NCH*512*8)  // 626688 ushort per plane (hi / lo)

using short8 = __attribute__((ext_vector_type(8))) short;
using short4v = __attribute__((ext_vector_type(4))) short;
using f32x4  = __attribute__((ext_vector_type(4))) float;

__device__ __forceinline__ float sigmoidf_(float x) {
  return 1.0f / (1.0f + __expf(-x));
}

// RNE fp32 -> bf16 bits
__device__ __forceinline__ unsigned short f32_to_bf16_rne(float f) {
  unsigned int u = __float_as_uint(f);
  unsigned int r = u + 0x7FFFu + ((u >> 16) & 1u);
  return (unsigned short)(r >> 16);
}
__device__ __forceinline__ float bf16_bits_to_f32(unsigned short b) {
  return __uint_as_float(((unsigned int)b) << 16);
}

// ---------------------------------------------------------------------------
// Pre-transpose W[4880,128] into MFMA B-fragment order, hi/lo bf16 planes.
// ---------------------------------------------------------------------------
__global__ __launch_bounds__(256) void k_prep_wt(
    const float* __restrict__ Wd, unsigned short* __restrict__ Wt) {
  const int u = blockIdx.x * 256 + threadIdx.x;   // 0 .. 78335 (NCH*512)
  const int c = u >> 9, rem = u & 511;
  const int nt = rem >> 6, lane = rem & 63;
  const int n = nt * 16 + (lane & 15);
  const int kb = c * 32 + ((lane >> 4) << 3);
  short8 h8, l8;
  #pragma unroll
  for (int j = 0; j < 8; ++j) {
    int k = kb + j;
    float v = (k < LEAF) ? Wd[(size_t)k * 128 + n] : 0.0f;
    unsigned short hb = f32_to_bf16_rne(v);
    unsigned short lb = f32_to_bf16_rne(v - bf16_bits_to_f32(hb));
    h8[j] = (short)hb;
    l8[j] = (short)lb;
  }
  *(short8*)&Wt[(size_t)u * 8] = h8;
  *(short8*)&Wt[(size_t)WT_PLANE + (size_t)u * 8] = l8;
}

// ---------------------------------------------------------------------------
// Big GEMM via MFMA, v6: BM=64 (double per-wave work).
// R9 post-mortem: v3/v4/v5 (LDS-dbuf, DMA-B, reg-B) ALL ~78-80us with every
// pipe <20% and bank-conflict count bit-identical -- none of {barrier drain,
// occupancy, LDS bytes, L2 BW (13 B/cyc/CU << 56)} is binding. The fit:
// wall/period ~6120cyc = waves-per-SIMD(8) x per-wave-chunk serial latency
// (~750cyc: ds_read 140 + 4x3-MFMA chains + repack + issue + barrier skew).
// time ~ total-wave-chunks x serial-latency / 1024 SIMDs; KSPLIT cancels --
// hence every BM=32 reshuffle was neutral.
// v6: BM=64 halves wave-chunk count; wave = 64Mx16N (4 msub, 12 MFMA in 4
// independent chains -- latency grows sublinearly). B L2 traffic also halves
// (each Wt read covers 2x the M rows). 500 blocks, launch_bounds(512,4) ->
// 2 blocks/CU (4 waves/SIMD). A staged 1 float4/thread (8 threads/row,
// 128B/row coalesced). Same vmcnt pipeline as v5: entering iter =
// [B(c)x2, A(c+1)]; issue B(c+1)x2, A(c+2); wait vmcnt(3) (tail 2/0).
// Arithmetic identical (3-MFMA hi/lo) -> absmax bit-identical.
// ---------------------------------------------------------------------------
__global__ __launch_bounds__(512, 4) void k_gemm_mfma(
    const float* __restrict__ Ax, const unsigned short* __restrict__ Wt,
    float* __restrict__ P) {
  __shared__ __align__(16) unsigned short As[2][4096];  // 16 KB [buf][plane*2048 + frag]
  const int tid  = threadIdx.x;
  const int lane = tid & 63;
  const int w    = tid >> 6;     // wave id = nt tile (16 cols each)
  const int M0   = blockIdx.x * 64;
  const int s    = blockIdx.y;
  const int c0   = (s * NCH) / KSPLIT;
  const int c1   = ((s + 1) * NCH) / KSPLIT;

  // A staging map (all 512 threads, uniform): row am = tid>>3, k-quad kq = tid&7.
  // 8 threads cover one row's 32 floats (128B contiguous, coalesced).
  const int am = tid >> 3;
  const int kq = tid & 7;
  const float* pA = Ax + (size_t)(M0 + am) * LEAF;
  // ushort index (within plane) matching the MFMA A-fragment read layout:
  // elem A[row][k] lives at (row>>4)*512 + ((row&15) + 16*(k>>3))*8 + (k&7)
  const int a_idx = (am >> 4) * 512 + ((am & 15) + 16 * (kq >> 1)) * 8 + (kq & 1) * 4;

  f32x4 acc[4];
  #pragma unroll
  for (int i = 0; i < 4; ++i) {
    #pragma unroll
    for (int q = 0; q < 4; ++q) acc[i][q] = 0.0f;
  }

  float4 rA_a, rA_b;                 // ping-pong A prefetch (depth 2)
  short8 bh_a, bl_a, bh_b, bl_b;     // ping-pong B fragments (depth 1)

  auto issueB = [&](int c, short8& bh, short8& bl) {
    const size_t o = ((size_t)c * 512 + w * 64 + lane) * 8;
    bh = *(const short8*)&Wt[o];
    bl = *(const short8*)&Wt[(size_t)WT_PLANE + o];
  };
  auto issueA = [&](int c, float4& ra) {
    int kk = c * 32 + kq * 4;
    kk = min(kk, LEAF - 4);            // clamp (no skip): uniform vmcnt counts;
    ra = *(const float4*)(pA + kk);    // clamped dup data x Wt zero rows = 0
  };
  auto storeA = [&](int p, float4 ra) {
    float v[4] = {ra.x, ra.y, ra.z, ra.w};
    short4v h4, l4;
    #pragma unroll
    for (int j = 0; j < 4; ++j) {
      unsigned short hb = f32_to_bf16_rne(v[j]);
      unsigned short lb = f32_to_bf16_rne(v[j] - bf16_bits_to_f32(hb));
      h4[j] = (short)hb;
      l4[j] = (short)lb;
    }
    *(short4v*)&As[p][a_idx] = h4;
    *(short4v*)&As[p][2048 + a_idx] = l4;
  };
  auto compute = [&](int p, const short8& bh, const short8& bl) {
    #pragma unroll
    for (int m = 0; m < 4; ++m) {
      short8 a_hi = *(const short8*)&As[p][m * 512 + lane * 8];
      short8 a_lo = *(const short8*)&As[p][2048 + m * 512 + lane * 8];
      acc[m] = __builtin_amdgcn_mfma_f32_16x16x32_bf16(a_hi, bl, acc[m], 0, 0, 0);
      acc[m] = __builtin_amdgcn_mfma_f32_16x16x32_bf16(a_lo, bh, acc[m], 0, 0, 0);
      acc[m] = __builtin_amdgcn_mfma_f32_16x16x32_bf16(a_hi, bh, acc[m], 0, 0, 0);
    }
  };

  // ---- prologue ----
  {
    float4 ta;
    issueA(c0, ta);
    asm volatile("s_waitcnt vmcnt(0)" ::: "memory");
    storeA(0, ta);
    issueB(c0, bh_a, bl_a);                      // 2 loads
    asm volatile("" ::: "memory");
    if (c0 + 1 < c1) issueA(c0 + 1, rA_a);       // 1 load
    asm volatile("s_waitcnt lgkmcnt(0)" ::: "memory");
    __builtin_amdgcn_s_barrier();
    asm volatile("" ::: "memory");
    // outstanding entering loop: [B(c0) x2, A(c0+1)]
  }

  // Per iter: outstanding on entry = [B(c) x2, A(c+1)] (from prev iter).
  // Issue B(c+1)x2, A(c+2); counted wait drains exactly the entry set;
  // compute with B(c); storeA(A(c+1)); lgkm; barrier.
#define GEMM_ITER(BHc, BLc, BHn, BLn, RAc, RAn)                               \
  {                                                                           \
    const int p = (c - c0) & 1;                                               \
    const bool has1 = (c + 1 < c1), has2 = (c + 2 < c1);                      \
    if (has1) { issueB(c + 1, BHn, BLn); asm volatile("" ::: "memory"); }     \
    if (has2) { issueA(c + 2, RAn);      asm volatile("" ::: "memory"); }     \
    if (has1) {                                                               \
      if (has2) { asm volatile("s_waitcnt vmcnt(3)" ::: "memory"); }          \
      else      { asm volatile("s_waitcnt vmcnt(2)" ::: "memory"); }          \
    } else      { asm volatile("s_waitcnt vmcnt(0)" ::: "memory"); }          \
    compute(p, BHc, BLc);                                                     \
    if (has1) storeA(p ^ 1, RAc);                                             \
    asm volatile("s_waitcnt lgkmcnt(0)" ::: "memory");                        \
    __builtin_amdgcn_s_barrier();                                             \
    asm volatile("" ::: "memory");                                            \
    ++c;                                                                      \
  }

  int c = c0;
  while (c < c1) {
    GEMM_ITER(bh_a, bl_a, bh_b, bl_b, rA_a, rA_b);
    if (c < c1) GEMM_ITER(bh_b, bl_b, bh_a, bl_a, rA_b, rA_a);
  }
#undef GEMM_ITER

  // epilogue: C/D layout col=lane&15, row=(lane>>4)*4+r ; cols = w*16..w*16+15
  float* outp = P + (size_t)s * ((size_t)M_TOT * 128);
  const int col0 = w * 16 + (lane & 15);
  #pragma unroll
  for (int m = 0; m < 4; ++m) {
    const int rbase = M0 + m * 16 + ((lane >> 4) << 2);
    #pragma unroll
    for (int r = 0; r < 4; ++r)
      outp[(size_t)(rbase + r) * 128 + col0] = acc[m][r];
  }
}

// ---------------------------------------------------------------------------
// Reduce KSPLIT partials + tanh (X aliases P slot 0; elementwise-safe).
// ---------------------------------------------------------------------------
__global__ __launch_bounds__(256) void k_reduce_tanh(
    float* __restrict__ P, float* __restrict__ X) {
  const size_t i = ((size_t)blockIdx.x * 256 + threadIdx.x) * 4;
  float4 a = *(const float4*)&P[i];
  #pragma unroll
  for (int s = 1; s < KSPLIT; ++s) {
    float4 b = *(const float4*)&P[(size_t)s * (M_TOT * 128) + i];
    a.x += b.x; a.y += b.y; a.z += b.z; a.w += b.w;
  }
  a.x = tanhf(a.x); a.y = tanhf(a.y); a.z = tanhf(a.z); a.w = tanhf(a.w);
  *(float4*)&X[i] = a;
}

// ---------------------------------------------------------------------------
// Generic small GEMM: C[M,N] = A[M,K] @ Bw[N,K]^T + bias  (opt sigmoid*mask)
// ---------------------------------------------------------------------------
template<int K, int ACT>
__global__ __launch_bounds__(256) void k_gemm_bn(
    const float* __restrict__ A, const float* __restrict__ Bw,
    const float* __restrict__ bias, const float* __restrict__ maskv,
    float* __restrict__ C, int N, int ldc) {
  __shared__ __align__(16) float Asm[32][K + 4];
  const int tid = threadIdx.x;
  const int m0 = blockIdx.x * 32;
  const int n0 = blockIdx.y * 64;
  constexpr int K4 = K / 4;

  #pragma unroll
  for (int i = 0; i < (32 * K4) / 256; ++i) {
    int idx = tid + i * 256;
    int row = idx / K4, k4 = idx % K4;
    float4 v = *(const float4*)&A[(size_t)(m0 + row) * K + k4 * 4];
    *(float4*)&Asm[row][k4 * 4] = v;
  }
  __syncthreads();

  const int n2 = tid & 31, mg = tid >> 5;
  const int n = n0 + n2 * 2;
  const int ns0 = min(n, N - 1), ns1 = min(n + 1, N - 1);
  const float* Bp0 = Bw + (size_t)ns0 * K;
  const float* Bp1 = Bw + (size_t)ns1 * K;

  float acc[4][2] = {};
  #pragma unroll 4
  for (int k = 0; k < K; k += 4) {
    float4 b0 = *(const float4*)&Bp0[k];
    float4 b1 = *(const float4*)&Bp1[k];
    #pragma unroll
    for (int r = 0; r < 4; ++r) {
      float4 a = *(const float4*)&Asm[mg * 4 + r][k];
      acc[r][0] += a.x * b0.x + a.y * b0.y + a.z * b0.z + a.w * b0.w;
      acc[r][1] += a.x * b1.x + a.y * b1.y + a.z * b1.z + a.w * b1.w;
    }
  }

  #pragma unroll
  for (int r = 0; r < 4; ++r) {
    int m = m0 + mg * 4 + r;
    #pragma unroll
    for (int c = 0; c < 2; ++c) {
      int nn = n + c;
      if (nn < N) {
        float v = acc[r][c] + bias[nn];
        if (ACT) v = sigmoidf_(v) * maskv[m];
        C[(size_t)m * ldc + nn] = v;
      }
    }
  }
}

// ---------------------------------------------------------------------------
// GRU scan v3 (R5-proven). One block per batch row; 512 threads.
// Weights pre-rotated at load (register arrays use unroll-constant indices
// only). n-gate bias INSIDE r*: n = tanh(xn + r*(Wn.h + bn)).
// ---------------------------------------------------------------------------
__global__ __launch_bounds__(512) void k_gru(
    const float* __restrict__ xW, const float* __restrict__ Whh,
    const float* __restrict__ bhh, float* __restrict__ Hout) {
  const int b = blockIdx.x;
  const int tid = threadIdx.x;
  const int j  = tid >> 2;
  const int qf = tid & 3;
  __shared__ __align__(16) float hs[2][128];

  float4 wr[8], wz[8], wn[8];
  {
    const float* pr = Whh + (size_t)j * 128 + qf * 32;
    const float* pz = Whh + (size_t)(j + 128) * 128 + qf * 32;
    const float* pn = Whh + (size_t)(j + 256) * 128 + qf * 32;
    #pragma unroll
    for (int k = 0; k < 8; ++k) {
      const int c = (k + qf * 2) & 7;   // rotation folded into the LOAD
      wr[k] = *(const float4*)(pr + c * 4);
      wz[k] = *(const float4*)(pz + c * 4);
      wn[k] = *(const float4*)(pn + c * 4);
    }
  }
  const float br = bhh[j], bz = bhh[j + 128], bn_ = bhh[j + 256];

  if (tid < 128) hs[0][tid] = 0.0f;
  const float* xwb = xW + (size_t)b * 50 * 384;
  float xr = 0.f, xz = 0.f, xn = 0.f;
  if (qf == 0) { xr = xwb[j]; xz = xwb[128 + j]; xn = xwb[256 + j]; }
  __syncthreads();

  int cur = 0;
  for (int t = 0; t < 50; ++t) {
    float nxr = 0.f, nxz = 0.f, nxn = 0.f;
    if (qf == 0 && t + 1 < 50) {
      const float* xwn = xwb + (size_t)(t + 1) * 384;
      nxr = xwn[j]; nxz = xwn[128 + j]; nxn = xwn[256 + j];
    }

    float ar = 0.f, az = 0.f, an = 0.f;
    #pragma unroll
    for (int k = 0; k < 8; ++k) {
      const int c = (k + qf * 2) & 7;   // runtime -> LDS address only
      float4 hv = *(const float4*)&hs[cur][qf * 32 + c * 4];
      ar += wr[k].x * hv.x + wr[k].y * hv.y + wr[k].z * hv.z + wr[k].w * hv.w;
      az += wz[k].x * hv.x + wz[k].y * hv.y + wz[k].z * hv.z + wz[k].w * hv.w;
      an += wn[k].x * hv.x + wn[k].y * hv.y + wn[k].z * hv.z + wn[k].w * hv.w;
    }
    ar += __shfl_xor(ar, 1); ar += __shfl_xor(ar, 2);
    az += __shfl_xor(az, 1); az += __shfl_xor(az, 2);
    an += __shfl_xor(an, 1); an += __shfl_xor(an, 2);

    if (qf == 0) {
      float r = sigmoidf_(xr + ar + br);
      float z = sigmoidf_(xz + az + bz);
      float nn = tanhf(xn + r * (an + bn_));   // bias INSIDE r*
      float h = (1.f - z) * nn + z * hs[cur][j];
      hs[cur ^ 1][j] = h;
      Hout[(size_t)(b * 50 + t) * 128 + j] = h;
    }
    __syncthreads();
    cur ^= 1;
    xr = nxr; xz = nxz; xn = nxn;
  }
}

// ---------------------------------------------------------------------------
// Attention: per (b,t) block (6400 blocks, 128 threads).
// ---------------------------------------------------------------------------
__global__ __launch_bounds__(128) void k_attn(
    const float* __restrict__ H2, const int* __restrict__ F,
    const float* __restrict__ emb, float* __restrict__ S) {
  const int m = blockIdx.x;
  const int tid = threadIdx.x;
  __shared__ __align__(16) float outs[128];
  __shared__ __align__(16) float Ls[64][132];
  __shared__ float hls[64];
  __shared__ float wts[64];
  __shared__ int fs[64];

  outs[tid] = H2[(size_t)m * 128 + tid];
  if (tid < 64) fs[tid] = F[(size_t)m * 64 + tid];
  __syncthreads();

  #pragma unroll
  for (int i = 0; i < 16; ++i) {
    int idx = tid + i * 128;
    int a = idx >> 5, c4 = idx & 31;
    float4 v = *(const float4*)&emb[(size_t)fs[a] * 128 + c4 * 4];
    *(float4*)&Ls[a][c4 * 4] = v;
  }
  __syncthreads();

  {
    const int a = tid >> 1, hf = tid & 1;
    float sum = 0.f;
    #pragma unroll
    for (int j = 0; j < 16; ++j) {
      float4 lv = *(const float4*)&Ls[a][hf * 64 + j * 4];
      float4 ov = *(const float4*)&outs[hf * 64 + j * 4];
      sum += lv.x * ov.x + lv.y * ov.y + lv.z * ov.z + lv.w * ov.w;
    }
    float other = __shfl_xor(sum, 1);
    sum += other;
    if (hf == 0) hls[a] = sum + (fs[a] > 0 ? 0.0f : -1e30f);
  }
  __syncthreads();

  if (tid < 64) {
    float v = hls[tid];
    float mx = v;
    #pragma unroll
    for (int o = 32; o; o >>= 1) mx = fmaxf(mx, __shfl_xor(mx, o));
    float e = __expf(v - mx);
    float sm = e;
    #pragma unroll
    for (int o = 32; o; o >>= 1) sm += __shfl_xor(sm, o);
    wts[tid] = e / sm;
  }
  __syncthreads();

  float kv = 0.f;
  #pragma unroll 8
  for (int a2 = 0; a2 < 64; ++a2) kv += wts[a2] * Ls[a2][tid];

  S[(size_t)m * 256 + tid] = outs[tid];
  S[(size_t)m * 256 + 128 + tid] = kv;
}

// ---------------------------------------------------------------------------
extern "C" void kernel_launch(void* const* d_in, const int* in_sizes, int n_in,
                              void* d_out, int out_size, void* d_ws, size_t ws_size,
                              hipStream_t stream) {
  const float* inputs_x  = (const float*)d_in[0];
  const int*   inputs_f  = (const int*)d_in[1];
  const float* mask_seqs = (const float*)d_in[2];
  const float* dag_emb   = (const float*)d_in[3];
  const float* embed_a   = (const float*)d_in[4];
  const float* Wih0 = (const float*)d_in[5];
  const float* Whh0 = (const float*)d_in[6];
  const float* bih0 = (const float*)d_in[7];
  const float* bhh0 = (const float*)d_in[8];
  const float* Wih1 = (const float*)d_in[9];
  const float* Whh1 = (const float*)d_in[10];
  const float* bih1 = (const float*)d_in[11];
  const float* bhh1 = (const float*)d_in[12];
  const float* fc_w = (const float*)d_in[13];
  const float* fc_b = (const float*)d_in[14];
  float* out = (float*)d_out;

  float* ws = (float*)d_ws;
  // Footprint identical to R5/R6 (proven): 5*819200 + 2457600 + 2*819200 floats.
  float* P  = ws;
  float* X  = P;                       // aliases P slot 0 (reduce in-place safe)
  float* S  = P + 819200;              // aliases P slots 1-2 (P dead after reduce)
  float* xW = ws + KSPLIT * 819200;
  float* H1 = xW + 2457600;
  float* H2 = H1 + 819200;
  // Wt (2.5 MB bf16) aliases H1+H2 (6.5 MB): dead before k_gru writes H1.
  unsigned short* Wt = (unsigned short*)H1;

  k_prep_wt<<<306, 256, 0, stream>>>(dag_emb, Wt);
  k_gemm_mfma<<<dim3(100, KSPLIT), 512, 0, stream>>>(inputs_x, Wt, P);
  k_reduce_tanh<<<800, 256, 0, stream>>>(P, X);
  k_gemm_bn<128, 0><<<dim3(200, 6), 256, 0, stream>>>(X, Wih0, bih0, nullptr, xW, 384, 384);
  k_gru<<<128, 512, 0, stream>>>(xW, Whh0, bhh0, H1);
  k_gemm_bn<128, 0><<<dim3(200, 6), 256, 0, stream>>>(H1, Wih1, bih1, nullptr, xW, 384, 384);
  k_gru<<<128, 512, 0, stream>>>(xW, Whh1, bhh1, H2);
  k_attn<<<6400, 128, 0, stream>>>(H2, inputs_f, embed_a, S);
  k_gemm_bn<256, 1><<<dim3(200, 5), 256, 0, stream>>>(S, fc_w, fc_b, mask_seqs, out, 283, 283);
}